// Round 12
// baseline (260.621 us; speedup 1.0000x reference)
//
#include <hip/hip_runtime.h>

// features: (16, 64, 65536) f32, coords: (16, 3, 65536) f32, resolution = 32
constexpr int Rr = 32;
constexpr int R2 = Rr * Rr;          // 1024
constexpr int R3 = Rr * Rr * Rr;     // 32768
constexpr int Bb = 16;
constexpr int Cc = 64;
constexpr int Nn = 65536;
constexpr int VOX_ELEMS = Bb * Cc * R3;    // 33,554,432
constexpr int NCELL = Bb * R3;             // 524,288
constexpr int CB = 4;                      // batches per chunk (voxT4 chunk = 67 MB, L3-resident)

// RTNE pack of two f32 into one u32 of 2x bf16 (lo = a, hi = b)
__device__ __forceinline__ unsigned pack_bf16(float a, float b)
{
    unsigned ua = __float_as_uint(a);
    unsigned ub = __float_as_uint(b);
    ua += 0x7FFFu + ((ua >> 16) & 1u);
    ub += 0x7FFFu + ((ub >> 16) & 1u);
    return (ua >> 16) | (ub & 0xFFFF0000u);
}

// ---------------- K0: zero cnt (2 MB) ----------------
__global__ __launch_bounds__(256) void zero_cnt_kernel(float4* __restrict__ base)
{
    int i = blockIdx.x * 256 + threadIdx.x;        // NCELL*4/16 elements
    base[i] = float4{0.0f, 0.0f, 0.0f, 0.0f};
}

// ---------------- K1: norm_coords + cell + within-cell rank k ----------------
__global__ __launch_bounds__(256) void vox_coords_kernel(
    const float* __restrict__ coords,
    float* __restrict__ norm_out,
    int* __restrict__ idx_out,
    int* __restrict__ cnt)
{
    int t = blockIdx.x * 256 + threadIdx.x;        // t = b*N + i
    int b = t >> 16;
    int i = t & (Nn - 1);

    const float* cp = coords + (size_t)b * 3 * Nn + i;
    float x = cp[0];
    float y = cp[Nn];
    float z = cp[2 * Nn];

    float nx = fminf(fmaxf((x + 1.0f) * 16.0f, 0.0f), 31.0f);
    float ny = fminf(fmaxf((y + 1.0f) * 16.0f, 0.0f), 31.0f);
    float nz = fminf(fmaxf((z + 1.0f) * 16.0f, 0.0f), 31.0f);

    float* np_ = norm_out + (size_t)b * 3 * Nn + i;
    np_[0]      = nx;
    np_[Nn]     = ny;
    np_[2 * Nn] = nz;

    int idx = (int)rintf(nx) * R2 + (int)rintf(ny) * Rr + (int)rintf(nz);

    int k = atomicAdd(&cnt[(b << 15) + idx], 1);   // within-cell rank
    idx_out[t] = (idx << 3) | min(k, 7);           // 15b cell | 3b clamped rank
}

// ---------------- K2: per chunk, pre-zero slot3 rows of overflow cells (cnt>4) ----------------
__global__ __launch_bounds__(256) void slot3zero_kernel(
    const int* __restrict__ cnt, unsigned short* __restrict__ voxT4, int b0)
{
    int g = blockIdx.x * 256 + threadIdx.x;        // CB*32768*8 threads
    int cellLoc = g >> 3;                          // chunk-local cell
    int p       = g & 7;
    if (cnt[(b0 << 15) + cellLoc] > 4)             // 2MB table, L2-resident
        *(float4*)(voxT4 + ((size_t)cellLoc << 8) + 192 + (p << 3)) =
            float4{0.0f, 0.0f, 0.0f, 0.0f};        // 8 ushorts = 16 B
}

// ---------------- K3: per chunk, coalesced read -> LDS transpose -> slotted row stores ----------------
__global__ __launch_bounds__(256) void tscatter_store_kernel(
    const float* __restrict__ feat,
    const int* __restrict__ idx_ws,
    const int* __restrict__ cnt,
    unsigned short* __restrict__ voxT4,    // bf16, chunk-local [cell][slot0..3][64ch]
    int b0)
{
    __shared__ float lds[64 * 65];                 // [n][c], stride 65
    __shared__ int   dest_sm[64];                  // ushort offset of the point's row
    __shared__ int   at_sm[64];                    // 1 = use atomic (overflow)
    int bb   = blockIdx.x >> 10;                   // chunk-local batch
    int b    = b0 + bb;
    int tile = blockIdx.x & 1023;
    int n0   = tile << 6;
    int t    = threadIdx.x;

    if (t < 64) {
        int e       = idx_ws[(b << 16) + n0 + t];
        int cellLoc = (bb << 15) + (e >> 3);
        int k       = e & 7;                       // clamped rank
        int cn      = cnt[(b << 15) + (e >> 3)];   // final count, L2-hot
        dest_sm[t] = (cellLoc << 8) + (min(k, 3) << 6);   // ushort units
        at_sm[t]   = (k >= 3 && cn > 4) ? 1 : 0;
    }

#pragma unroll
    for (int q = 0; q < 4; ++q) {
        int c  = (t >> 4) + (q << 4);
        int n4 = (t & 15) << 2;
        float4 v = *(const float4*)(feat + (((size_t)(b * Cc + c)) << 16) + n0 + n4);
        lds[(n4 + 0) * 65 + c] = v.x;
        lds[(n4 + 1) * 65 + c] = v.y;
        lds[(n4 + 2) * 65 + c] = v.z;
        lds[(n4 + 3) * 65 + c] = v.w;
    }
    __syncthreads();

    // per wave-instr: lanes 0-31 commit row n, lanes 32-63 row n+1 (128 B bf16 rows)
    int wave = t >> 6, lane = t & 63;
    int hi = lane >> 5;                // 0 or 1
    int m  = lane & 31;                // channel-pair index
#pragma unroll
    for (int kk = 0; kk < 8; ++kk) {
        int n = (wave << 4) + (kk << 1) + hi;
        float f0 = lds[n * 65 + (m << 1) + 0];
        float f1 = lds[n * 65 + (m << 1) + 1];
        unsigned pk = pack_bf16(f0, f1);
        unsigned short* addr = voxT4 + (size_t)dest_sm[n] + (m << 1);
        if (at_sm[n]) {
            asm volatile("global_atomic_pk_add_bf16 %0, %1, off"
                         :: "v"(addr), "v"(pk) : "memory");
        } else {
            *(unsigned*)addr = pk;                 // plain 4 B store, full-line rows
        }
    }
}

// ---------------- K4: per chunk, merge slots (masked, f32) + divide + transpose ----------------
__global__ __launch_bounds__(256) void merge_transpose_kernel(
    const unsigned short* __restrict__ voxT4,
    const int* __restrict__ cnt,
    float* __restrict__ vox,
    int b0)
{
    __shared__ float lds[64 * 65];                 // [cell][ch], stride 65
    int bb   = blockIdx.x >> 9;                    // chunk-local batch
    int b    = b0 + bb;
    int tile = blockIdx.x & 511;
    int v0   = tile << 6;
    int t    = threadIdx.x;
    int cl   = t >> 2;                             // cell-local 0..63
    int q    = t & 3;                              // ch group of 16

    int cellLoc = (bb << 15) + v0 + cl;
    int cn      = cnt[(b << 15) + v0 + cl];
    int kmax    = min(cn, 4);

    float acc[16];
#pragma unroll
    for (int j = 0; j < 16; ++j) acc[j] = 0.0f;

    const unsigned short* base = voxT4 + ((size_t)cellLoc << 8) + (q << 4);
    for (int k = 0; k < kmax; ++k) {
        uint4 w0 = *(const uint4*)(base + (k << 6));
        uint4 w1 = *(const uint4*)(base + (k << 6) + 8);
        const unsigned* w = &w0.x;
#pragma unroll
        for (int j = 0; j < 4; ++j) {
            acc[2 * j + 0] += __uint_as_float(w[j] << 16);
            acc[2 * j + 1] += __uint_as_float(w[j] & 0xFFFF0000u);
        }
        const unsigned* w2 = &w1.x;
#pragma unroll
        for (int j = 0; j < 4; ++j) {
            acc[8 + 2 * j + 0] += __uint_as_float(w2[j] << 16);
            acc[8 + 2 * j + 1] += __uint_as_float(w2[j] & 0xFFFF0000u);
        }
    }

    float inv = cn ? 1.0f / (float)cn : 0.0f;      // empty cell -> 0 (== 0/1e-5)
#pragma unroll
    for (int j = 0; j < 16; ++j)
        lds[cl * 65 + (q << 4) + j] = acc[j] * inv;
    __syncthreads();

    int wave = t >> 6, lane = t & 63;
#pragma unroll
    for (int k = 0; k < 16; ++k) {
        int c = (wave << 4) + k;
        vox[(((size_t)(b * Cc + c)) << 15) + v0 + lane] = lds[lane * 65 + c];
    }
}

extern "C" void kernel_launch(void* const* d_in, const int* in_sizes, int n_in,
                              void* d_out, int out_size, void* d_ws, size_t ws_size,
                              hipStream_t stream)
{
    const float* features = (const float*)d_in[0];
    const float* coords   = (const float*)d_in[1];

    float* out      = (float*)d_out;
    float* vox      = out;
    float* norm_out = out + VOX_ELEMS;

    // ws layout: cnt (2MB) | idx (4MB) | voxT4 bf16 4-slot CHUNK (67MB, reused, NOT zeroed)
    char* ws = (char*)d_ws;
    int*            cnt    = (int*)ws;            ws += (size_t)NCELL * 4;
    int*            idx_ws = (int*)ws;            ws += (size_t)Bb * Nn * 4;
    unsigned short* voxT4  = (unsigned short*)ws; // CB * 32768 cells * 4 slots * 64 ch bf16

    zero_cnt_kernel<<<NCELL * 4 / 16 / 256, 256, 0, stream>>>((float4*)cnt);
    vox_coords_kernel<<<(Bb * Nn) / 256, 256, 0, stream>>>(coords, norm_out, idx_ws, cnt);

    for (int b0 = 0; b0 < Bb; b0 += CB) {
        slot3zero_kernel<<<CB * R3 * 8 / 256, 256, 0, stream>>>(cnt, voxT4, b0);
        tscatter_store_kernel<<<CB * 1024, 256, 0, stream>>>(features, idx_ws, cnt, voxT4, b0);
        merge_transpose_kernel<<<CB * 512, 256, 0, stream>>>(voxT4, cnt, vox, b0);
    }
}

// Round 13
// 225.736 us; speedup vs baseline: 1.1545x; 1.1545x over previous
//
#include <hip/hip_runtime.h>

// features: (16, 64, 65536) f32, coords: (16, 3, 65536) f32, resolution = 32
constexpr int Rr = 32;
constexpr int R2 = Rr * Rr;          // 1024
constexpr int R3 = Rr * Rr * Rr;     // 32768
constexpr int Bb = 16;
constexpr int Cc = 64;
constexpr int Nn = 65536;
constexpr int VOX_ELEMS = Bb * Cc * R3;    // 33,554,432
constexpr int NCELL = Bb * R3;             // 524,288

// RTNE pack of two f32 into one u32 of 2x bf16 (lo = a, hi = b)
__device__ __forceinline__ unsigned pack_bf16(float a, float b)
{
    unsigned ua = __float_as_uint(a);
    unsigned ub = __float_as_uint(b);
    ua += 0x7FFFu + ((ua >> 16) & 1u);
    ub += 0x7FFFu + ((ub >> 16) & 1u);
    return (ua >> 16) | (ub & 0xFFFF0000u);
}

// ---------------- K0: zero cnt (2 MB) ----------------
__global__ __launch_bounds__(256) void zero_cnt_kernel(float4* __restrict__ base)
{
    int i = blockIdx.x * 256 + threadIdx.x;        // NCELL*4/16 elements
    base[i] = float4{0.0f, 0.0f, 0.0f, 0.0f};
}

// ---------------- K1: norm_coords + cell + within-cell rank k ----------------
__global__ __launch_bounds__(256) void vox_coords_kernel(
    const float* __restrict__ coords,
    float* __restrict__ norm_out,
    int* __restrict__ idx_out,
    int* __restrict__ cnt)
{
    int t = blockIdx.x * 256 + threadIdx.x;        // t = b*N + i
    int b = t >> 16;
    int i = t & (Nn - 1);

    const float* cp = coords + (size_t)b * 3 * Nn + i;
    float x = cp[0];
    float y = cp[Nn];
    float z = cp[2 * Nn];

    float nx = fminf(fmaxf((x + 1.0f) * 16.0f, 0.0f), 31.0f);
    float ny = fminf(fmaxf((y + 1.0f) * 16.0f, 0.0f), 31.0f);
    float nz = fminf(fmaxf((z + 1.0f) * 16.0f, 0.0f), 31.0f);

    float* np_ = norm_out + (size_t)b * 3 * Nn + i;
    np_[0]      = nx;
    np_[Nn]     = ny;
    np_[2 * Nn] = nz;

    int idx = (int)rintf(nx) * R2 + (int)rintf(ny) * Rr + (int)rintf(nz);

    int k = atomicAdd(&cnt[(b << 15) + idx], 1);   // within-cell rank
    idx_out[t] = (idx << 3) | min(k, 7);           // 15b cell | 3b clamped rank
}

// ---------------- K2: pre-zero slot3 rows of overflow cells (cnt>4, ~5%) ----------------
__global__ __launch_bounds__(256) void slot3zero_kernel(
    const int* __restrict__ cnt, unsigned short* __restrict__ voxT4)
{
    int g = blockIdx.x * 256 + threadIdx.x;        // NCELL*8 threads
    int cell = g >> 3;
    int p    = g & 7;
    if (cnt[cell] > 4)                             // 2MB table, L2-resident
        *(float4*)(voxT4 + ((size_t)cell << 8) + 192 + (p << 3)) =
            float4{0.0f, 0.0f, 0.0f, 0.0f};        // 8 ushorts = 16 B
}

// ---------------- K3: coalesced read -> LDS transpose -> slotted 128B row stores ----------------
__global__ __launch_bounds__(256) void tscatter_store_kernel(
    const float* __restrict__ feat,
    const int* __restrict__ idx_ws,
    const int* __restrict__ cnt,
    unsigned short* __restrict__ voxT4)    // bf16, [cell][slot0..3][64ch]
{
    __shared__ float lds[64 * 65];                 // [n][c], stride 65
    __shared__ int   dest_sm[64];                  // ushort offset of the point's row
    __shared__ int   at_sm[64];                    // 1 = use atomic (overflow)
    int b    = blockIdx.x >> 10;
    int tile = blockIdx.x & 1023;
    int n0   = tile << 6;
    int t    = threadIdx.x;

    if (t < 64) {
        int e    = idx_ws[(b << 16) + n0 + t];
        int cell = (b << 15) + (e >> 3);
        int k    = e & 7;                          // clamped rank
        int cn   = cnt[cell];                      // final count, L2-hot
        dest_sm[t] = (cell << 8) + (min(k, 3) << 6);   // ushort units
        at_sm[t]   = (k >= 3 && cn > 4) ? 1 : 0;
    }

#pragma unroll
    for (int q = 0; q < 4; ++q) {
        int c  = (t >> 4) + (q << 4);
        int n4 = (t & 15) << 2;
        float4 v = *(const float4*)(feat + (((size_t)(b * Cc + c)) << 16) + n0 + n4);
        lds[(n4 + 0) * 65 + c] = v.x;
        lds[(n4 + 1) * 65 + c] = v.y;
        lds[(n4 + 2) * 65 + c] = v.z;
        lds[(n4 + 3) * 65 + c] = v.w;
    }
    __syncthreads();

    // per wave-instr: lanes 0-31 commit row n, lanes 32-63 row n+1 (128 B bf16 rows)
    int wave = t >> 6, lane = t & 63;
    int hi = lane >> 5;                // 0 or 1
    int m  = lane & 31;                // channel-pair index
#pragma unroll
    for (int kk = 0; kk < 8; ++kk) {
        int n = (wave << 4) + (kk << 1) + hi;
        float f0 = lds[n * 65 + (m << 1) + 0];
        float f1 = lds[n * 65 + (m << 1) + 1];
        unsigned pk = pack_bf16(f0, f1);
        unsigned short* addr = voxT4 + (size_t)dest_sm[n] + (m << 1);
        if (at_sm[n]) {
            asm volatile("global_atomic_pk_add_bf16 %0, %1, off"
                         :: "v"(addr), "v"(pk) : "memory");
        } else {
            *(unsigned*)addr = pk;                 // plain 4 B store, full-line rows
        }
    }
}

// ---------------- K4: merge slots (fixed unroll, predicated loads, f32) + transpose ----------------
__global__ __launch_bounds__(256) void merge_transpose_kernel(
    const unsigned short* __restrict__ voxT4,
    const int* __restrict__ cnt,
    float* __restrict__ vox)
{
    __shared__ float lds[64 * 65];                 // [cell][ch], stride 65
    int b    = blockIdx.x >> 9;
    int tile = blockIdx.x & 511;
    int v0   = tile << 6;
    int t    = threadIdx.x;
    int cl   = t >> 2;                             // cell-local 0..63
    int q    = t & 3;                              // ch group of 16

    int cell = (b << 15) + v0 + cl;
    int cn   = cnt[cell];

    const unsigned short* base = voxT4 + ((size_t)cell << 8) + (q << 4);

    // All (predicated) loads issued up front -> one waitcnt, full MLP.
    // Masked lanes (k >= cn) fetch nothing; their values are zero-filled.
    uint4 wa[4], wb[4];
#pragma unroll
    for (int k = 0; k < 4; ++k) {
        if (k < cn) {
            wa[k] = *(const uint4*)(base + (k << 6));
            wb[k] = *(const uint4*)(base + (k << 6) + 8);
        } else {
            wa[k] = uint4{0u, 0u, 0u, 0u};
            wb[k] = uint4{0u, 0u, 0u, 0u};
        }
    }

    float acc[16];
#pragma unroll
    for (int j = 0; j < 16; ++j) acc[j] = 0.0f;

#pragma unroll
    for (int k = 0; k < 4; ++k) {
        const unsigned* w = &wa[k].x;
#pragma unroll
        for (int j = 0; j < 4; ++j) {
            acc[2 * j + 0] += __uint_as_float(w[j] << 16);
            acc[2 * j + 1] += __uint_as_float(w[j] & 0xFFFF0000u);
        }
        const unsigned* w2 = &wb[k].x;
#pragma unroll
        for (int j = 0; j < 4; ++j) {
            acc[8 + 2 * j + 0] += __uint_as_float(w2[j] << 16);
            acc[8 + 2 * j + 1] += __uint_as_float(w2[j] & 0xFFFF0000u);
        }
    }

    float inv = cn ? 1.0f / (float)cn : 0.0f;      // empty cell -> 0 (== 0/1e-5)
#pragma unroll
    for (int j = 0; j < 16; ++j)
        lds[cl * 65 + (q << 4) + j] = acc[j] * inv;
    __syncthreads();

    int wave = t >> 6, lane = t & 63;
#pragma unroll
    for (int k = 0; k < 16; ++k) {
        int c = (wave << 4) + k;
        vox[(((size_t)(b * Cc + c)) << 15) + v0 + lane] = lds[lane * 65 + c];
    }
}

extern "C" void kernel_launch(void* const* d_in, const int* in_sizes, int n_in,
                              void* d_out, int out_size, void* d_ws, size_t ws_size,
                              hipStream_t stream)
{
    const float* features = (const float*)d_in[0];
    const float* coords   = (const float*)d_in[1];

    float* out      = (float*)d_out;
    float* vox      = out;
    float* norm_out = out + VOX_ELEMS;

    // ws layout: cnt (2MB) | idx (4MB) | voxT4 bf16 4-slot (268MB, NOT zeroed)
    char* ws = (char*)d_ws;
    int*            cnt    = (int*)ws;            ws += (size_t)NCELL * 4;
    int*            idx_ws = (int*)ws;            ws += (size_t)Bb * Nn * 4;
    unsigned short* voxT4  = (unsigned short*)ws; // NCELL * 4 slots * 64 ch bf16

    zero_cnt_kernel<<<NCELL * 4 / 16 / 256, 256, 0, stream>>>((float4*)cnt);
    vox_coords_kernel<<<(Bb * Nn) / 256, 256, 0, stream>>>(coords, norm_out, idx_ws, cnt);
    slot3zero_kernel<<<NCELL * 8 / 256, 256, 0, stream>>>(cnt, voxT4);
    tscatter_store_kernel<<<Bb * 1024, 256, 0, stream>>>(features, idx_ws, cnt, voxT4);
    merge_transpose_kernel<<<Bb * 512, 256, 0, stream>>>(voxT4, cnt, vox);
}